// Round 11
// baseline (362.380 us; speedup 1.0000x reference)
//
#include <hip/hip_runtime.h>
#include <hip/hip_bf16.h>
#include <hip/hip_fp16.h>

#define E4M3_MAX 240.0f

typedef __attribute__((ext_vector_type(8))) __bf16 bf16x8;
typedef __attribute__((ext_vector_type(16))) float f32x16;
typedef unsigned short ushort_t;

__device__ __forceinline__ void gload_lds16(const void* g, void* l) {
  __builtin_amdgcn_global_load_lds(
      (const __attribute__((address_space(1))) void*)g,
      (__attribute__((address_space(3))) void*)l,
      16, 0, 0);
}

// ---------------- amax over |weight| ----------------
__global__ void amax_abs_kernel(const float* __restrict__ w, int n4,
                                unsigned* __restrict__ amax_bits) {
  float m = 0.0f;
  const float4* w4 = (const float4*)w;
  int stride = gridDim.x * blockDim.x;
  for (int i = blockIdx.x * blockDim.x + threadIdx.x; i < n4; i += stride) {
    float4 v = w4[i];
    m = fmaxf(m, fmaxf(fmaxf(fabsf(v.x), fabsf(v.y)),
                       fmaxf(fabsf(v.z), fabsf(v.w))));
  }
  for (int off = 32; off > 0; off >>= 1)
    m = fmaxf(m, __shfl_down(m, off, 64));
  __shared__ float smax[4];
  int l = threadIdx.x & 63, wv = threadIdx.x >> 6;
  if (l == 0) smax[wv] = m;
  __syncthreads();
  if (threadIdx.x == 0) {
    float bm = fmaxf(fmaxf(smax[0], smax[1]), fmaxf(smax[2], smax[3]));
    atomicMax(amax_bits, __float_as_uint(bm));
  }
}

// ---------------- quantize weight -> bf16 qw ----------------
__global__ void quant_weight_kernel(const float* __restrict__ w,
                                    const unsigned* __restrict__ amax_bits,
                                    ushort_t* __restrict__ qw, int n4) {
  float amax = __uint_as_float(*amax_bits);
  float scale = fmaxf(amax / E4M3_MAX, 1e-10f);
  const float4* w4 = (const float4*)w;
  ushort4* q4 = (ushort4*)qw;
  int stride = gridDim.x * blockDim.x;
  for (int i = blockIdx.x * blockDim.x + threadIdx.x; i < n4; i += stride) {
    float4 v = w4[i];
    float r[4] = {v.x, v.y, v.z, v.w};
    ushort_t o[4];
#pragma unroll
    for (int j = 0; j < 4; ++j) {
      float s = fminf(fmaxf(r[j] / scale, -E4M3_MAX), E4M3_MAX);
      s = __half2float(__float2half(s));   // fp16 round-trip (RNE)
      float q = rintf(s * 8.0f) * 0.125f;  // mantissa grid, half-to-even
      q = fminf(fmaxf(q, -E4M3_MAX), E4M3_MAX);
      __hip_bfloat16 h = __float2bfloat16(q * scale);
      o[j] = *(ushort_t*)&h;
    }
    ushort4 ov = {o[0], o[1], o[2], o[3]};
    q4[i] = ov;
  }
}

// ---------------- convert x fp32 -> bf16 ----------------
__global__ void cvt_bf16_kernel(const float* __restrict__ x,
                                ushort_t* __restrict__ xb, int n4) {
  const float4* x4 = (const float4*)x;
  ushort4* o4 = (ushort4*)xb;
  int stride = gridDim.x * blockDim.x;
  for (int i = blockIdx.x * blockDim.x + threadIdx.x; i < n4; i += stride) {
    float4 v = x4[i];
    __hip_bfloat16 h0 = __float2bfloat16(v.x);
    __hip_bfloat16 h1 = __float2bfloat16(v.y);
    __hip_bfloat16 h2 = __float2bfloat16(v.z);
    __hip_bfloat16 h3 = __float2bfloat16(v.w);
    ushort4 o = {*(ushort_t*)&h0, *(ushort_t*)&h1,
                 *(ushort_t*)&h2, *(ushort_t*)&h3};
    o4[i] = o;
  }
}

// == 256x256 bf16 GEMM — 32x32x16, BK=32, 4-buffer LDS, cross-tile frag pipeline ==
// C = A * Bt^T + bias.  A: [8192][4096] bf16, Bt: [4096][4096] bf16, C fp32.
// 8 waves (2M x 4N).  Per tile t: { vmcnt(4); barrier; stage tile t+3 (4 gloads,
// buffer idle since t-1); ds_read tile t+1 frags (12 b128, into the OTHER frag
// set); MMA16 on tile t's frags }.  Compiler inserts counted lgkm waits before
// next tile's MMA -> DS pipe services t+1's reads UNDER t's MFMA cluster.
// One barrier + one vmcnt per tile; drained loads are always >=2 tiles old.

#define BAR() do { asm volatile("" ::: "memory"); \
                   __builtin_amdgcn_s_barrier(); \
                   asm volatile("" ::: "memory"); } while (0)
#define VMC8() asm volatile("s_waitcnt vmcnt(8)" ::: "memory")
#define VMC4() asm volatile("s_waitcnt vmcnt(4)" ::: "memory")
#define VMC0() asm volatile("s_waitcnt vmcnt(0)" ::: "memory")
#define SB0()  __builtin_amdgcn_sched_barrier(0)

__global__ __launch_bounds__(512, 2) void gemm256_pipe4(
    const ushort_t* __restrict__ A, const ushort_t* __restrict__ Bt,
    const float* __restrict__ bias, float* __restrict__ C) {
  constexpr int K = 4096, N = 4096;
  // 4 buffers x [half:128 rows][128x32 elem] x 2B = 64 KB per matrix
  __shared__ __align__(16) ushort_t As[4][2][4096];
  __shared__ __align__(16) ushort_t Bs[4][2][4096];

  const int tid = threadIdx.x;
  const int wid = tid >> 6, lane = tid & 63;
  const int wm = wid >> 2, wn = wid & 3;     // 2 x 4 wave grid
  const int l31 = lane & 31, lk2 = lane >> 5;

  // XCD swizzle (nwg = 512, divisible by 8)
  int bid = blockIdx.x;
  int swz = (bid & 7) * 64 + (bid >> 3);
  int bm = swz >> 4, bn = swz & 15;          // nbn = 16

  const ushort_t* Ab = A + (size_t)bm * 256 * K;
  const ushort_t* Bb = Bt + (size_t)bn * 256 * K;

  // staging: slot s = q*512+tid; row = s>>2 (4 x 16B granules per 32-elem row);
  // source granule c = (s&3) ^ sigma2(row), sigma2(r) = (r&3) ^ ((r>>2)&3)
  int offG[2];
#pragma unroll
  for (int q = 0; q < 2; ++q) {
    int s = q * 512 + tid;
    int row = s >> 2;
    int c = (s & 3) ^ (row & 3) ^ ((row >> 2) & 3);
    offG[q] = row * K + c * 8;
  }

  // stage one full 256x32 tile of A or B (2 gloads each)
#define STAGE_A(bufL, kt)                                                  \
  do { _Pragma("unroll") for (int q = 0; q < 2; ++q)                       \
    gload_lds16(Ab + (size_t)(kt) * 32 + offG[q],                          \
                &As[bufL][q][tid * 8]); } while (0)
#define STAGE_B(bufL, kt)                                                  \
  do { _Pragma("unroll") for (int q = 0; q < 2; ++q)                       \
    gload_lds16(Bb + (size_t)(kt) * 32 + offG[q],                          \
                &Bs[bufL][q][tid * 8]); } while (0)

  // ds_read addressing: granule = (ks*2 + lk2) ^ sigma2(row); row offsets
  // (rg*32, cg*32, (wn&1)*64) are multiples of 4 -> sigma2 is lane-constant.
  const int bhalf = wn >> 1;
  const int brow0 = (wn & 1) * 64;
  const int sig2 = (l31 & 3) ^ ((l31 >> 2) & 3);
  int xk2[2];
#pragma unroll
  for (int ks = 0; ks < 2; ++ks) xk2[ks] = ((ks * 2 + lk2) ^ sig2) * 8;

  bf16x8 af0[4][2], af1[4][2], bf0[2][2], bf1[2][2];
  f32x16 acc[4][2] = {};

  // 12 ds_reads for one tile into frag set S
#define RD12(S, bufL)                                                      \
  do {                                                                     \
    _Pragma("unroll") for (int cg = 0; cg < 2; ++cg)                       \
      _Pragma("unroll") for (int ks = 0; ks < 2; ++ks)                     \
        bf##S[cg][ks] = *(const bf16x8*)                                   \
            &Bs[bufL][bhalf][(brow0 + cg * 32 + l31) * 32 + xk2[ks]];      \
    _Pragma("unroll") for (int rg = 0; rg < 4; ++rg)                       \
      _Pragma("unroll") for (int ks = 0; ks < 2; ++ks)                     \
        af##S[rg][ks] = *(const bf16x8*)                                   \
            &As[bufL][wm][((rg) * 32 + l31) * 32 + xk2[ks]];               \
  } while (0)

  // 16 MFMA on frag set S (compiler inserts the lgkm waits for S's reads)
#define MMA16(S)                                                           \
  do { __builtin_amdgcn_s_setprio(1);                                      \
    _Pragma("unroll") for (int rg = 0; rg < 4; ++rg)                       \
      _Pragma("unroll") for (int ks = 0; ks < 2; ++ks) {                   \
        acc[rg][0] = __builtin_amdgcn_mfma_f32_32x32x16_bf16(              \
            af##S[rg][ks], bf##S[0][ks], acc[rg][0], 0, 0, 0);             \
        acc[rg][1] = __builtin_amdgcn_mfma_f32_32x32x16_bf16(              \
            af##S[rg][ks], bf##S[1][ks], acc[rg][1], 0, 0, 0);             \
      }                                                                    \
    __builtin_amdgcn_s_setprio(0); } while (0)

  // One tile: certify tile t+1 landed (vmcnt->barrier), stage t+3, read t+1,
  // compute t.  VMCX drains loads issued 2 tiles ago.
#define TILE(VMCX, DO_S, SBUF, skt, DO_R, RBUF, RS, CS)                    \
  do {                                                                     \
    VMCX; BAR();                                                           \
    if (DO_S) { STAGE_A(SBUF, skt); STAGE_B(SBUF, skt); }                  \
    if (DO_R) RD12(RS, RBUF);                                              \
    SB0();                                                                 \
    MMA16(CS);                                                             \
  } while (0)

  // ---- prologue: stage tiles 0,1,2; certify tile 0; preload frags(set0) ----
  STAGE_A(0, 0); STAGE_B(0, 0);
  STAGE_A(1, 1); STAGE_B(1, 1);
  STAGE_A(2, 2); STAGE_B(2, 2);
  VMC8(); BAR();          // tile 0 landed; tiles 1,2 (8 loads) in flight
  RD12(0, 0);             // frags for tile 0 into set 0

  // ---- main loop: tiles 0..123, 4 tiles/iter ----
  for (int t = 0; t < 124; t += 4) {
    TILE(VMC4(), 1, 3, t + 3, 1, 1, 1, 0);   // tile t
    TILE(VMC4(), 1, 0, t + 4, 1, 2, 0, 1);   // tile t+1
    TILE(VMC4(), 1, 1, t + 5, 1, 3, 1, 0);   // tile t+2
    TILE(VMC4(), 1, 2, t + 6, 1, 0, 0, 1);   // tile t+3
  }
  // ---- peeled tail: tiles 124..127 ----
  TILE(VMC4(), 1, 3, 127, 1, 1, 1, 0);       // t=124: stage 127, read 125
  TILE(VMC4(), 0, 0, 0,   1, 2, 0, 1);       // t=125: read 126
  TILE(VMC0(), 0, 0, 0,   1, 3, 1, 0);       // t=126: drain, read 127
  MMA16(1);                                  // t=127

  // ---- C write + bias (32x32 D: col = lane&31, row = (r&3)+8*(r>>2)+4*(lane>>5)) ----
  float* Cb = C + (size_t)(bm * 256 + wm * 128) * N + bn * 256 + wn * 64;
#pragma unroll
  for (int cg = 0; cg < 2; ++cg) {
    int n = cg * 32 + l31;
    float bv = bias[bn * 256 + wn * 64 + n];
#pragma unroll
    for (int rg = 0; rg < 4; ++rg) {
#pragma unroll
      for (int r = 0; r < 16; ++r) {
        int row = rg * 32 + (r & 3) + 8 * (r >> 2) + 4 * lk2;
        Cb[(size_t)row * N + n] = acc[rg][cg][r] + bv;
      }
    }
  }
}

extern "C" void kernel_launch(void* const* d_in, const int* in_sizes, int n_in,
                              void* d_out, int out_size, void* d_ws, size_t ws_size,
                              hipStream_t stream) {
  const float* x = (const float*)d_in[0];     // [4,2048,4096] fp32
  const float* wt = (const float*)d_in[1];    // [4096,4096] fp32
  const float* bias = (const float*)d_in[2];  // [4096] fp32
  float* out = (float*)d_out;                 // [4,2048,4096] fp32

  const int DIN = 4096;
  const int NW = in_sizes[1];                 // 16777216
  const int M = in_sizes[0] / DIN;            // 8192

  char* ws = (char*)d_ws;
  unsigned* amax_bits = (unsigned*)ws;
  ushort_t* qw = (ushort_t*)(ws + 256);                    // bf16 [4096][4096]
  ushort_t* xb = (ushort_t*)(ws + 256 + (size_t)NW * 2);   // bf16 [8192][4096]

  hipMemsetAsync(amax_bits, 0, 4, stream);
  hipLaunchKernelGGL(amax_abs_kernel, dim3(1024), dim3(256), 0, stream,
                     wt, NW / 4, amax_bits);
  hipLaunchKernelGGL(quant_weight_kernel, dim3(2048), dim3(256), 0, stream,
                     wt, amax_bits, qw, NW / 4);
  hipLaunchKernelGGL(cvt_bf16_kernel, dim3(2048), dim3(256), 0, stream,
                     x, xb, (M * DIN) / 4);

  hipLaunchKernelGGL(gemm256_pipe4, dim3(512), dim3(512), 0, stream,
                     xb, qw, bias, out);
}

// Round 12
// 351.330 us; speedup vs baseline: 1.0315x; 1.0315x over previous
//
#include <hip/hip_runtime.h>
#include <hip/hip_bf16.h>
#include <hip/hip_fp16.h>

#define E4M3_MAX 240.0f

typedef __attribute__((ext_vector_type(8))) __bf16 bf16x8;
typedef __attribute__((ext_vector_type(4))) float f32x4;
typedef unsigned short ushort_t;

__device__ __forceinline__ void gload_lds16(const void* g, void* l) {
  __builtin_amdgcn_global_load_lds(
      (const __attribute__((address_space(1))) void*)g,
      (__attribute__((address_space(3))) void*)l,
      16, 0, 0);
}

// ---------------- amax over |weight| ----------------
__global__ void amax_abs_kernel(const float* __restrict__ w, int n4,
                                unsigned* __restrict__ amax_bits) {
  float m = 0.0f;
  const float4* w4 = (const float4*)w;
  int stride = gridDim.x * blockDim.x;
  for (int i = blockIdx.x * blockDim.x + threadIdx.x; i < n4; i += stride) {
    float4 v = w4[i];
    m = fmaxf(m, fmaxf(fmaxf(fabsf(v.x), fabsf(v.y)),
                       fmaxf(fabsf(v.z), fabsf(v.w))));
  }
  for (int off = 32; off > 0; off >>= 1)
    m = fmaxf(m, __shfl_down(m, off, 64));
  __shared__ float smax[4];
  int l = threadIdx.x & 63, wv = threadIdx.x >> 6;
  if (l == 0) smax[wv] = m;
  __syncthreads();
  if (threadIdx.x == 0) {
    float bm = fmaxf(fmaxf(smax[0], smax[1]), fmaxf(smax[2], smax[3]));
    atomicMax(amax_bits, __float_as_uint(bm));
  }
}

// ---------------- quantize weight -> bf16 qw ----------------
__global__ void quant_weight_kernel(const float* __restrict__ w,
                                    const unsigned* __restrict__ amax_bits,
                                    ushort_t* __restrict__ qw, int n4) {
  float amax = __uint_as_float(*amax_bits);
  float scale = fmaxf(amax / E4M3_MAX, 1e-10f);
  const float4* w4 = (const float4*)w;
  ushort4* q4 = (ushort4*)qw;
  int stride = gridDim.x * blockDim.x;
  for (int i = blockIdx.x * blockDim.x + threadIdx.x; i < n4; i += stride) {
    float4 v = w4[i];
    float r[4] = {v.x, v.y, v.z, v.w};
    ushort_t o[4];
#pragma unroll
    for (int j = 0; j < 4; ++j) {
      float s = fminf(fmaxf(r[j] / scale, -E4M3_MAX), E4M3_MAX);
      s = __half2float(__float2half(s));   // fp16 round-trip (RNE)
      float q = rintf(s * 8.0f) * 0.125f;  // mantissa grid, half-to-even
      q = fminf(fmaxf(q, -E4M3_MAX), E4M3_MAX);
      __hip_bfloat16 h = __float2bfloat16(q * scale);
      o[j] = *(ushort_t*)&h;
    }
    ushort4 ov = {o[0], o[1], o[2], o[3]};
    q4[i] = ov;
  }
}

// ---------------- convert x fp32 -> bf16 ----------------
__global__ void cvt_bf16_kernel(const float* __restrict__ x,
                                ushort_t* __restrict__ xb, int n4) {
  const float4* x4 = (const float4*)x;
  ushort4* o4 = (ushort4*)xb;
  int stride = gridDim.x * blockDim.x;
  for (int i = blockIdx.x * blockDim.x + threadIdx.x; i < n4; i += stride) {
    float4 v = x4[i];
    __hip_bfloat16 h0 = __float2bfloat16(v.x);
    __hip_bfloat16 h1 = __float2bfloat16(v.y);
    __hip_bfloat16 h2 = __float2bfloat16(v.z);
    __hip_bfloat16 h3 = __float2bfloat16(v.w);
    ushort4 o = {*(ushort_t*)&h0, *(ushort_t*)&h1,
                 *(ushort_t*)&h2, *(ushort_t*)&h3};
    o4[i] = o;
  }
}

// == 256x256 bf16 GEMM — m201-faithful: 16x16x32, C-quadrant phases, vmcnt(6) ==
// C = A * Bt^T + bias.  A: [8192][4096] bf16, Bt: [4096][4096] bf16, C fp32.
// 8 waves (2M x 4N), per-wave 128x64, BK=64, dbuf LDS 128 KiB.
// Per tile (4 phases): Ph1 reads A[H0](8)+B[J0](4) [12, lgkm8]; Ph2 reads
// B[J1](4); Ph3 reads A[H1](8); Ph4 reads nothing (bfP,afO reused).  Each
// phase: reads; stage half-tile; [lgkm8]; BAR; lgkm0; setprio1; 16 MFMA
// (one C-quadrant x K=64); setprio0; BAR.  vmcnt(6) at Ph4/Ph8 only — 3
// half-tiles (6 loads) stay in flight; drained loads are >=4 phases old.

#define BAR() do { asm volatile("" ::: "memory"); \
                   __builtin_amdgcn_s_barrier(); \
                   asm volatile("" ::: "memory"); } while (0)
#define LGKM0() asm volatile("s_waitcnt lgkmcnt(0)" ::: "memory")
#define LGKM8() asm volatile("s_waitcnt lgkmcnt(8)" ::: "memory")
#define VMC6() asm volatile("s_waitcnt vmcnt(6)" ::: "memory")
#define VMC8() asm volatile("s_waitcnt vmcnt(8)" ::: "memory")
#define VMC0() asm volatile("s_waitcnt vmcnt(0)" ::: "memory")
#define NOVM() do {} while (0)

__global__ __launch_bounds__(512, 2) void gemm256_q(
    const ushort_t* __restrict__ A, const ushort_t* __restrict__ Bt,
    const float* __restrict__ bias, float* __restrict__ C) {
  constexpr int K = 4096, N = 4096;
  __shared__ __align__(16) ushort_t As[2][2][8192];
  __shared__ __align__(16) ushort_t Bs[2][2][8192];

  const int tid = threadIdx.x;
  const int wid = tid >> 6, lane = tid & 63;
  const int wm = wid >> 2, wn = wid & 3;     // 2 x 4 wave grid
  const int lk = lane >> 4, lr = lane & 15;

  // XCD swizzle (nwg = 512, divisible by 8)
  int bid = blockIdx.x;
  int swz = (bid & 7) * 64 + (bid >> 3);
  int bm = swz >> 4, bn = swz & 15;          // nbn = 16

  const ushort_t* Ab = A + (size_t)bm * 256 * K;
  const ushort_t* Bb = Bt + (size_t)bn * 256 * K;

  // staging: slot s = q*512+tid; row = s>>3; granule c = (s&7)^(row&7)
  int offG[2];
#pragma unroll
  for (int q = 0; q < 2; ++q) {
    int s = q * 512 + tid;
    int row = s >> 3;
    int c = (s & 7) ^ (row & 7);
    offG[q] = row * K + c * 8;
  }

#define STAGE_AH(buf, kt, h)                                               \
  do { _Pragma("unroll") for (int q = 0; q < 2; ++q)                       \
    gload_lds16(Ab + (size_t)(h) * 128 * K + (kt) * 64 + offG[q],          \
                &As[buf][h][(q * 512 + wid * 64) * 8]); } while (0)
#define STAGE_BH(buf, kt, h)                                               \
  do { _Pragma("unroll") for (int q = 0; q < 2; ++q)                       \
    gload_lds16(Bb + (size_t)(h) * 128 * K + (kt) * 64 + offG[q],          \
                &Bs[buf][h][(q * 512 + wid * 64) * 8]); } while (0)

  // swizzled ds_read addressing (R2-verified, 0 conflicts for this pattern)
  const int abase = lr * 64;
  const int bbase = (wn & 1) * 4096 + lr * 64;
  const int bhalf = wn >> 1;
  const int xk0 = ((lk) ^ (lr & 7)) * 8;
  const int xk1 = ((4 + lk) ^ (lr & 7)) * 8;

  // frag sets: afE = fi 0-3 (H0), afO = fi 4-7 (H1); bfP = fj 0-1 (J0),
  // bfQ = fj 2-3 (J1).  acc[8][4] f32x4.
  bf16x8 afE[4][2], afO[4][2], bfP[2][2], bfQ[2][2];
  f32x4 acc[8][4] = {};

#define RDA(AF, fi0, cb)                                                   \
  do { _Pragma("unroll") for (int i = 0; i < 4; ++i) {                     \
    AF[i][0] = *(const bf16x8*)&As[cb][wm][abase + ((fi0) + i) * 1024 + xk0]; \
    AF[i][1] = *(const bf16x8*)&As[cb][wm][abase + ((fi0) + i) * 1024 + xk1]; \
  } } while (0)
#define RDB(BF, fj0, cb)                                                   \
  do { _Pragma("unroll") for (int j = 0; j < 2; ++j) {                     \
    BF[j][0] = *(const bf16x8*)&Bs[cb][bhalf][bbase + ((fj0) + j) * 1024 + xk0]; \
    BF[j][1] = *(const bf16x8*)&Bs[cb][bhalf][bbase + ((fj0) + j) * 1024 + xk1]; \
  } } while (0)

  // one C-quadrant x K=64: 4 fi x 2 fj x 2 ks = 16 MFMA
#define MMAQ(AF, fi0, BF, fj0)                                             \
  do { __builtin_amdgcn_s_setprio(1);                                      \
    _Pragma("unroll") for (int i = 0; i < 4; ++i)                          \
      _Pragma("unroll") for (int j = 0; j < 2; ++j) {                      \
        acc[(fi0) + i][(fj0) + j] = __builtin_amdgcn_mfma_f32_16x16x32_bf16( \
            AF[i][0], BF[j][0], acc[(fi0) + i][(fj0) + j], 0, 0, 0);       \
        acc[(fi0) + i][(fj0) + j] = __builtin_amdgcn_mfma_f32_16x16x32_bf16( \
            AF[i][1], BF[j][1], acc[(fi0) + i][(fj0) + j], 0, 0, 0);       \
      }                                                                    \
    __builtin_amdgcn_s_setprio(0); } while (0)

  // Body for tiles (u [buf0], u+1 [buf1]).  Stages:
  //   Ph1: Ah1(u+1)->b1 (S1)      Ph3: Bh0(u+2)->b0 (S3)
  //   Ph4: Bh1(u+2)+Ah0(u+2)->b0  Ph5: Ah1(u+2)->b0 (S45)
  //   Ph7: Bh0(u+3)->b1           Ph8: Bh1(u+3)+Ah0(u+3)->b1 (S78)
  // vmcnt(6) at Ph4/Ph8 retires everything except the 3 newest half-tiles.
#define BODY(u, S1, S3, S45, S78, VM4, VM8)                                \
  do {                                                                     \
    /* Ph1 */                                                              \
    RDA(afE, 0, 0); RDB(bfP, 0, 0);                                        \
    if (S1) STAGE_AH(1, (u) + 1, 1);                                       \
    LGKM8(); BAR(); LGKM0(); MMAQ(afE, 0, bfP, 0); BAR();                  \
    /* Ph2 */                                                              \
    RDB(bfQ, 2, 0);                                                        \
    BAR(); LGKM0(); MMAQ(afE, 0, bfQ, 2); BAR();                           \
    /* Ph3 */                                                              \
    RDA(afO, 4, 0);                                                        \
    if (S3) STAGE_BH(0, (u) + 2, 0);                                       \
    BAR(); LGKM0(); MMAQ(afO, 4, bfQ, 2); BAR();                           \
    /* Ph4 */                                                              \
    if (S45) { STAGE_BH(0, (u) + 2, 1); STAGE_AH(0, (u) + 2, 0); }         \
    VM4; BAR(); MMAQ(afO, 4, bfP, 0); BAR();                               \
    /* Ph5 */                                                              \
    RDA(afE, 0, 1); RDB(bfP, 0, 1);                                        \
    if (S45) STAGE_AH(0, (u) + 2, 1);                                      \
    LGKM8(); BAR(); LGKM0(); MMAQ(afE, 0, bfP, 0); BAR();                  \
    /* Ph6 */                                                              \
    RDB(bfQ, 2, 1);                                                        \
    BAR(); LGKM0(); MMAQ(afE, 0, bfQ, 2); BAR();                           \
    /* Ph7 */                                                              \
    RDA(afO, 4, 1);                                                        \
    if (S78) STAGE_BH(1, (u) + 3, 0);                                      \
    BAR(); LGKM0(); MMAQ(afO, 4, bfQ, 2); BAR();                           \
    /* Ph8 */                                                              \
    if (S78) { STAGE_BH(1, (u) + 3, 1); STAGE_AH(1, (u) + 3, 0); }         \
    VM8; BAR(); MMAQ(afO, 4, bfP, 0); BAR();                               \
  } while (0)

  // ---- prologue: tiles 0 (buf0) and 1 (buf1) fully staged ----
  STAGE_BH(0, 0, 0); STAGE_BH(0, 0, 1);
  STAGE_AH(0, 0, 0); STAGE_AH(0, 0, 1);
  STAGE_BH(1, 1, 0); STAGE_BH(1, 1, 1);
  STAGE_AH(1, 1, 0); STAGE_AH(1, 1, 1);
  VMC8();   // tile 0 retired; tile 1's 8 loads in flight (retired @ body0-Ph4)
  BAR();

  // ---- body 0 (u=0): no Ph1-stage (tile 1 fully pre-staged) ----
  BODY(0, 0, 1, 1, 1, VMC6(), VMC6());
  // ---- bodies 1..30 (u=2..60): steady state ----
  for (int u = 2; u < 62; u += 2)
    BODY(u, 1, 1, 1, 1, VMC6(), VMC6());
  // ---- body 31 (u=62): stage only Ah1(63)@Ph1; drain at Ph4 ----
  BODY(62, 1, 0, 0, 0, VMC0(), NOVM());

  // ---- C write + bias (16x16 D: col = lane&15 -> n, row = lk*4 + reg -> m) ----
  float* Cb = C + (size_t)(bm * 256 + wm * 128) * N + bn * 256 + wn * 64;
#pragma unroll
  for (int fj = 0; fj < 4; ++fj) {
    int n = fj * 16 + lr;
    float bv = bias[bn * 256 + wn * 64 + n];
#pragma unroll
    for (int fi = 0; fi < 8; ++fi) {
      int m0 = fi * 16 + lk * 4;
#pragma unroll
      for (int r = 0; r < 4; ++r)
        Cb[(size_t)(m0 + r) * N + n] = acc[fi][fj][r] + bv;
    }
  }
}

extern "C" void kernel_launch(void* const* d_in, const int* in_sizes, int n_in,
                              void* d_out, int out_size, void* d_ws, size_t ws_size,
                              hipStream_t stream) {
  const float* x = (const float*)d_in[0];     // [4,2048,4096] fp32
  const float* wt = (const float*)d_in[1];    // [4096,4096] fp32
  const float* bias = (const float*)d_in[2];  // [4096] fp32
  float* out = (float*)d_out;                 // [4,2048,4096] fp32

  const int DIN = 4096;
  const int NW = in_sizes[1];                 // 16777216
  const int M = in_sizes[0] / DIN;            // 8192

  char* ws = (char*)d_ws;
  unsigned* amax_bits = (unsigned*)ws;
  ushort_t* qw = (ushort_t*)(ws + 256);                    // bf16 [4096][4096]
  ushort_t* xb = (ushort_t*)(ws + 256 + (size_t)NW * 2);   // bf16 [8192][4096]

  hipMemsetAsync(amax_bits, 0, 4, stream);
  hipLaunchKernelGGL(amax_abs_kernel, dim3(1024), dim3(256), 0, stream,
                     wt, NW / 4, amax_bits);
  hipLaunchKernelGGL(quant_weight_kernel, dim3(2048), dim3(256), 0, stream,
                     wt, amax_bits, qw, NW / 4);
  hipLaunchKernelGGL(cvt_bf16_kernel, dim3(2048), dim3(256), 0, stream,
                     x, xb, (M * DIN) / 4);

  hipLaunchKernelGGL(gemm256_q, dim3(512), dim3(512), 0, stream,
                     xb, qw, bias, out);
}